// Round 4
// baseline (107.953 us; speedup 1.0000x reference)
//
#include <hip/hip_runtime.h>
#include <math.h>

// MaskedCrossEntropyLoss: N rows x ncls f32 logits, K selected classes.
// loss = mean over valid rows of [ log(sum_sel exp(logit)) - logit[target] ].
//
// Max-free masked logsumexp (inputs O(1) normal => exp safe in fp32).
// One 64-lane wave handles 4 row-pairs (8 rows = 4 KB) per iteration:
// lanes 0-31 -> even row, 32-63 -> odd row; lane j loads float4 j of its row.
// 4 loads in flight per wave; 4 independent 5-step shuffle-sum chains
// interleave to hide DS-pipe latency.

#define UNROLL 4

__global__ __launch_bounds__(256, 8) void mce_rows_kernel(
    const float* __restrict__ logits,
    const int*   __restrict__ targets,
    const int*   __restrict__ cidx,
    int n, int ncls, int K,
    float* __restrict__ psum,
    float* __restrict__ pcnt,
    int npairwaves)
{
    // ---- 128-bit membership mask, built once per block ----
    __shared__ unsigned int smask[4];
    if (threadIdx.x < 4) smask[threadIdx.x] = 0u;
    __syncthreads();
    for (int i = (int)threadIdx.x; i < K; i += (int)blockDim.x) {
        const int c = cidx[i];
        atomicOr(&smask[(c >> 5) & 3], 1u << (c & 31));
    }
    __syncthreads();
    const unsigned int m0 = smask[0], m1 = smask[1], m2 = smask[2], m3 = smask[3];

    const int lane = threadIdx.x & 63;
    const int half = lane >> 5;          // which row of the pair
    const int j    = lane & 31;          // float4-group within the row
    const int wid  = (int)((blockIdx.x * blockDim.x + threadIdx.x) >> 6);

    // 4-bit membership for this lane's classes 4j..4j+3 (loop-invariant)
    const int sel = j >> 3;
    const unsigned int mword = (sel == 0) ? m0 : (sel == 1) ? m1 : (sel == 2) ? m2 : m3;
    const unsigned int mw = (mword >> ((4 * j) & 31)) & 0xFu;

    float acc = 0.0f;
    float cnt = 0.0f;

    const int npairs = (n + 1) >> 1;
    const int step   = UNROLL * npairwaves;

    for (int p0 = UNROLL * wid; p0 < npairs; p0 += step) {
        float4 v[UNROLL];
        int    t[UNROLL];
        bool   ok[UNROLL];
        int    rr[UNROLL];

        #pragma unroll
        for (int u = 0; u < UNROLL; ++u) {
            const int p = p0 + u;
            const int r = 2 * p + half;
            rr[u] = r;
            ok[u] = (p < npairs) && (r < n);
            v[u]  = make_float4(0.f, 0.f, 0.f, 0.f);
            t[u]  = -1;
        }
        #pragma unroll
        for (int u = 0; u < UNROLL; ++u) {
            if (ok[u]) {
                v[u] = reinterpret_cast<const float4*>(
                           logits + (size_t)rr[u] * (size_t)ncls)[j];
                t[u] = targets[rr[u]];
            }
        }

        // masked exp-sums (no max shift)
        float e[UNROLL];
        #pragma unroll
        for (int u = 0; u < UNROLL; ++u) {
            float s = 0.f;
            s += (mw & 1u) ? __expf(v[u].x) : 0.f;
            s += (mw & 2u) ? __expf(v[u].y) : 0.f;
            s += (mw & 4u) ? __expf(v[u].z) : 0.f;
            s += (mw & 8u) ? __expf(v[u].w) : 0.f;
            e[u] = s;
        }

        // 4 independent shuffle-sum chains, interleaved
        #pragma unroll
        for (int s = 16; s >= 1; s >>= 1) {
            #pragma unroll
            for (int u = 0; u < UNROLL; ++u) e[u] += __shfl_xor(e[u], s);
        }

        #pragma unroll
        for (int u = 0; u < UNROLL; ++u) {
            // validity: target in class_indices
            const int tw = (t[u] >> 5) & 3;
            const unsigned int vw = (tw == 0) ? m0 : (tw == 1) ? m1 : (tw == 2) ? m2 : m3;
            const bool valid = ok[u] && t[u] >= 0 && t[u] < ncls &&
                               (((vw >> (t[u] & 31)) & 1u) != 0u);
            const int ts = valid ? t[u] : 0;
            const int t3 = ts & 3;
            const float x = (t3 == 0) ? v[u].x : (t3 == 1) ? v[u].y
                          : (t3 == 2) ? v[u].z : v[u].w;
            const float tv = __shfl(x, (lane & 32) + (ts >> 2));
            if (j == 0 && valid) {
                acc += __logf(e[u]) - tv;
                cnt += 1.0f;
            }
        }
    }

    // wave sum (lanes 0 and 32 hold partials)
    #pragma unroll
    for (int s = 32; s >= 1; s >>= 1) {
        acc += __shfl_xor(acc, s);
        cnt += __shfl_xor(cnt, s);
    }

    __shared__ float ls[4];
    __shared__ float lc[4];
    const int w = threadIdx.x >> 6;
    if (lane == 0) { ls[w] = acc; lc[w] = cnt; }
    __syncthreads();
    if (threadIdx.x == 0) {
        float s = 0.0f, c = 0.0f;
        const int nw = (int)(blockDim.x >> 6);
        for (int i = 0; i < nw; ++i) { s += ls[i]; c += lc[i]; }
        psum[blockIdx.x] = s;
        pcnt[blockIdx.x] = c;
    }
}

__global__ __launch_bounds__(256) void mce_final_kernel(
    const float* __restrict__ psum,
    const float* __restrict__ pcnt,
    int nblk,
    float* __restrict__ out)
{
    __shared__ float ss[256];
    __shared__ float sc[256];
    float s = 0.0f, c = 0.0f;
    for (int i = threadIdx.x; i < nblk; i += blockDim.x) { s += psum[i]; c += pcnt[i]; }
    ss[threadIdx.x] = s;
    sc[threadIdx.x] = c;
    __syncthreads();
    for (int st = 128; st > 0; st >>= 1) {
        if ((int)threadIdx.x < st) {
            ss[threadIdx.x] += ss[threadIdx.x + st];
            sc[threadIdx.x] += sc[threadIdx.x + st];
        }
        __syncthreads();
    }
    if (threadIdx.x == 0) out[0] = ss[0] / fmaxf(sc[0], 1.0f);
}

extern "C" void kernel_launch(void* const* d_in, const int* in_sizes, int n_in,
                              void* d_out, int out_size, void* d_ws, size_t ws_size,
                              hipStream_t stream) {
    const float* logits  = (const float*)d_in[0];
    const int*   targets = (const int*)d_in[1];
    const int*   cidx    = (const int*)d_in[2];

    const int n    = in_sizes[1];              // rows
    const int ncls = in_sizes[0] / n;          // 128
    const int K    = in_sizes[2];              // 64

    const int BLOCK      = 256;
    const int NBLK       = 2048;               // 8 blocks/CU, fully resident
    const int npairwaves = NBLK * (BLOCK / 64);

    float* psum = (float*)d_ws;                // NBLK floats
    float* pcnt = psum + NBLK;                 // NBLK floats

    mce_rows_kernel<<<NBLK, BLOCK, 0, stream>>>(logits, targets, cidx,
                                                n, ncls, K, psum, pcnt, npairwaves);
    mce_final_kernel<<<1, 256, 0, stream>>>(psum, pcnt, NBLK, (float*)d_out);
}

// Round 5
// 100.755 us; speedup vs baseline: 1.0714x; 1.0714x over previous
//
#include <hip/hip_runtime.h>
#include <math.h>

// MaskedCrossEntropyLoss: N rows x ncls f32 logits, K selected classes.
// loss = mean over valid rows of [ log(sum_sel exp(logit)) - logit[target] ].
//
// Max-free masked logsumexp (inputs O(1) normal => exp safe in fp32).
// Layout: 8 lanes per row, 8 rows per wave-iteration (4 KB).
//   lane = 8*rg + k:  rg = row-in-group (0..7), k = sub-column (0..7).
//   Lane loads float4 indices {k, k+8, k+16, k+24} of its row = 16 classes.
//   Row reduction = 3-step shfl_xor within the 8-lane group (vs 5-step/row
//   in the half-wave layout) -> 4 DS ops per 8 rows instead of 24.

__global__ __launch_bounds__(256, 8) void mce_rows8_kernel(
    const float* __restrict__ logits,
    const int*   __restrict__ targets,
    const int*   __restrict__ cidx,
    int n, int ncls, int K,
    float* __restrict__ psum,
    float* __restrict__ pcnt,
    int nwaves)
{
    // ---- 128-bit membership mask, built once per block ----
    __shared__ unsigned int smask[4];
    if (threadIdx.x < 4) smask[threadIdx.x] = 0u;
    __syncthreads();
    for (int i = (int)threadIdx.x; i < K; i += (int)blockDim.x) {
        const int c = cidx[i];
        atomicOr(&smask[(c >> 5) & 3], 1u << (c & 31));
    }
    __syncthreads();
    const unsigned int m0 = smask[0], m1 = smask[1], m2 = smask[2], m3 = smask[3];

    const int lane = threadIdx.x & 63;
    const int rg   = lane >> 3;         // row within the 8-row tile
    const int k    = lane & 7;          // float4 sub-column
    const int wid  = (int)((blockIdx.x * blockDim.x + threadIdx.x) >> 6);

    // Per-register 4-bit masks: register q holds float4 #(k+8q) = classes
    // 4k+32q .. 4k+32q+3  -> word q of the mask, bits 4k..4k+3.
    const unsigned int mw0 = (m0 >> (4 * k)) & 0xFu;
    const unsigned int mw1 = (m1 >> (4 * k)) & 0xFu;
    const unsigned int mw2 = (m2 >> (4 * k)) & 0xFu;
    const unsigned int mw3 = (m3 >> (4 * k)) & 0xFu;

    float acc = 0.0f;
    float cnt = 0.0f;

    const int ntiles = (n + 7) >> 3;
    for (int tile = wid; tile < ntiles; tile += nwaves) {
        const int row = tile * 8 + rg;
        const bool ok = (row < n);

        float4 v0 = make_float4(0.f,0.f,0.f,0.f);
        float4 v1 = v0, v2 = v0, v3 = v0;
        int t = -1;
        if (ok) {
            const float4* rowp = reinterpret_cast<const float4*>(
                                     logits + (size_t)row * (size_t)ncls);
            v0 = rowp[k];
            v1 = rowp[k + 8];
            v2 = rowp[k + 16];
            v3 = rowp[k + 24];
            t  = targets[row];
        }

        // masked exp-sum over this lane's 16 classes
        float s = 0.f;
        s += (mw0 & 1u) ? __expf(v0.x) : 0.f;
        s += (mw0 & 2u) ? __expf(v0.y) : 0.f;
        s += (mw0 & 4u) ? __expf(v0.z) : 0.f;
        s += (mw0 & 8u) ? __expf(v0.w) : 0.f;
        s += (mw1 & 1u) ? __expf(v1.x) : 0.f;
        s += (mw1 & 2u) ? __expf(v1.y) : 0.f;
        s += (mw1 & 4u) ? __expf(v1.z) : 0.f;
        s += (mw1 & 8u) ? __expf(v1.w) : 0.f;
        s += (mw2 & 1u) ? __expf(v2.x) : 0.f;
        s += (mw2 & 2u) ? __expf(v2.y) : 0.f;
        s += (mw2 & 4u) ? __expf(v2.z) : 0.f;
        s += (mw2 & 8u) ? __expf(v2.w) : 0.f;
        s += (mw3 & 1u) ? __expf(v3.x) : 0.f;
        s += (mw3 & 2u) ? __expf(v3.y) : 0.f;
        s += (mw3 & 4u) ? __expf(v3.z) : 0.f;
        s += (mw3 & 8u) ? __expf(v3.w) : 0.f;

        // 3-step row reduce within the 8-lane group
        s += __shfl_xor(s, 1);
        s += __shfl_xor(s, 2);
        s += __shfl_xor(s, 4);

        // validity: target in class_indices
        const int tw = (t >> 5) & 3;
        const unsigned int vw = (tw == 0) ? m0 : (tw == 1) ? m1 : (tw == 2) ? m2 : m3;
        const bool valid = ok && t >= 0 && t < ncls && (((vw >> (t & 31)) & 1u) != 0u);

        // target logit: float4 index f=t>>2 lives in lane (group | f&7), reg f>>3
        const int ts = valid ? t : 0;
        const int f  = ts >> 2;
        const int q  = f >> 3;
        const int e3 = ts & 3;
        const float c0 = (e3 == 0) ? v0.x : (e3 == 1) ? v0.y : (e3 == 2) ? v0.z : v0.w;
        const float c1 = (e3 == 0) ? v1.x : (e3 == 1) ? v1.y : (e3 == 2) ? v1.z : v1.w;
        const float c2 = (e3 == 0) ? v2.x : (e3 == 1) ? v2.y : (e3 == 2) ? v2.z : v2.w;
        const float c3 = (e3 == 0) ? v3.x : (e3 == 1) ? v3.y : (e3 == 2) ? v3.z : v3.w;
        const float x  = (q == 0) ? c0 : (q == 1) ? c1 : (q == 2) ? c2 : c3;
        const float tv = __shfl(x, (lane & 56) | (f & 7));

        if (k == 0 && valid) {
            acc += __logf(s) - tv;
            cnt += 1.0f;
        }
    }

    // wave sum (8 lanes per wave hold partials)
    #pragma unroll
    for (int st = 32; st >= 1; st >>= 1) {
        acc += __shfl_xor(acc, st);
        cnt += __shfl_xor(cnt, st);
    }

    __shared__ float ls[4];
    __shared__ float lc[4];
    const int w = threadIdx.x >> 6;
    if (lane == 0) { ls[w] = acc; lc[w] = cnt; }
    __syncthreads();
    if (threadIdx.x == 0) {
        float ssum = 0.0f, c = 0.0f;
        const int nw = (int)(blockDim.x >> 6);
        for (int i = 0; i < nw; ++i) { ssum += ls[i]; c += lc[i]; }
        psum[blockIdx.x] = ssum;
        pcnt[blockIdx.x] = c;
    }
}

__global__ __launch_bounds__(256) void mce_final_kernel(
    const float* __restrict__ psum,
    const float* __restrict__ pcnt,
    int nblk,
    float* __restrict__ out)
{
    __shared__ float ss[256];
    __shared__ float sc[256];
    float s = 0.0f, c = 0.0f;
    for (int i = threadIdx.x; i < nblk; i += blockDim.x) { s += psum[i]; c += pcnt[i]; }
    ss[threadIdx.x] = s;
    sc[threadIdx.x] = c;
    __syncthreads();
    for (int st = 128; st > 0; st >>= 1) {
        if ((int)threadIdx.x < st) {
            ss[threadIdx.x] += ss[threadIdx.x + st];
            sc[threadIdx.x] += sc[threadIdx.x + st];
        }
        __syncthreads();
    }
    if (threadIdx.x == 0) out[0] = ss[0] / fmaxf(sc[0], 1.0f);
}

extern "C" void kernel_launch(void* const* d_in, const int* in_sizes, int n_in,
                              void* d_out, int out_size, void* d_ws, size_t ws_size,
                              hipStream_t stream) {
    const float* logits  = (const float*)d_in[0];
    const int*   targets = (const int*)d_in[1];
    const int*   cidx    = (const int*)d_in[2];

    const int n    = in_sizes[1];              // rows
    const int ncls = in_sizes[0] / n;          // 128
    const int K    = in_sizes[2];              // 64

    const int BLOCK  = 256;
    const int NBLK   = 2048;                   // 8192 waves, 8 blocks/CU
    const int nwaves = NBLK * (BLOCK / 64);

    float* psum = (float*)d_ws;                // NBLK floats
    float* pcnt = psum + NBLK;                 // NBLK floats

    mce_rows8_kernel<<<NBLK, BLOCK, 0, stream>>>(logits, targets, cidx,
                                                 n, ncls, K, psum, pcnt, nwaves);
    mce_final_kernel<<<1, 256, 0, stream>>>(psum, pcnt, NBLK, (float*)d_out);
}